// Round 13
// baseline (473.911 us; speedup 1.0000x reference)
//
#include <hip/hip_runtime.h>
#include <hip/hip_fp16.h>

#define VOCAB 32000
#define D 256
#define NSTEPS 12
#define BATCH 8
#define SEQ 512

// Uniform scan chunking: 32 chunks x 16 outputs, WARM=12 (validated R6/R7:
// warm-12 from pos>=4 gives absmax bit-identical to full-exact runs).
// pstart may be negative; ctx=0 at pos<=0 self-resets the recurrence.
#define OUTLEN 16
#define WARM 12
#define ITERS (OUTLEN + WARM)    // 28 (vs R4's 32 -> -12.5% critical path)
#define NCHUNK (SEQ / OUTLEN)    // 32 -> 256 blocks, 1/CU

typedef _Float16 f16x8 __attribute__((ext_vector_type(8)));
typedef float f32x4 __attribute__((ext_vector_type(4)));

// gelu(x) = 0.5 x (1 + erf(x/sqrt(2))); erf via A&S 7.1.26 (|err|<=1.5e-7).
__device__ __forceinline__ float gelu_fast(float x) {
    float y = x * 0.70710678118654752440f;
    float a = fabsf(y);
    float t = __builtin_amdgcn_rcpf(fmaf(0.3275911f, a, 1.0f));
    float p = fmaf(t, 1.061405429f, -1.453152027f);
    p = fmaf(t, p, 1.421413741f);
    p = fmaf(t, p, -0.284496736f);
    p = fmaf(t, p, 0.254829592f);
    p *= t;
    float e = __expf(-a * a);
    float erf_y = copysignf(fmaf(-p, e, 1.0f), y);
    return 0.5f * x * (1.0f + erf_y);
}

// cross-lane helpers (all VALU, no DS port).
__device__ __forceinline__ float dpp_xor1(float v) {
    int r = __builtin_amdgcn_update_dpp(0, __float_as_int(v), 0xB1, 0xf, 0xf, true);
    return __int_as_float(r);
}
__device__ __forceinline__ float dpp_xor2(float v) {
    int r = __builtin_amdgcn_update_dpp(0, __float_as_int(v), 0x4E, 0xf, 0xf, true);
    return __int_as_float(r);
}
__device__ __forceinline__ float dpp_ror4(float v) {
    int r = __builtin_amdgcn_update_dpp(0, __float_as_int(v), 0x124, 0xf, 0xf, true);
    return __int_as_float(r);
}
__device__ __forceinline__ float dpp_ror8(float v) {
    int r = __builtin_amdgcn_update_dpp(0, __float_as_int(v), 0x128, 0xf, 0xf, true);
    return __int_as_float(r);
}

// ---------------------------------------------------------------------------
// Phase A scan — R4 structure (register-blocked O=4/J=16, DPP reduce, merged
// barrier) with uniform 28-iter chunking (OUTLEN=16, WARM=12).
// ---------------------------------------------------------------------------
__global__ __launch_bounds__(1024) void scan_kernel(
    const int* __restrict__ ids, const float* __restrict__ emb,
    const float* __restrict__ W, const float* __restrict__ ps,
    float* __restrict__ states)
{
    const int chunk = blockIdx.x;
    const int b = blockIdx.y;
    const int t = (int)threadIdx.x;
    const int og = t >> 4;             // 0..63
    const int jc = t & 15;             // 0..15
    const int i_mine = og * 4 + (jc & 3);
    const bool writer = (jc < 4);

    float4 wreg[4][4];
    #pragma unroll
    for (int m = 0; m < 4; ++m) {
        const float4* wrow = (const float4*)(W + (og * 4 + m) * D + jc * 16);
        #pragma unroll
        for (int q = 0; q < 4; ++q) wreg[m][q] = wrow[q];
    }

    __shared__ __align__(16) float sbuf[2][16 * 20];

    const int first_out = chunk * OUTLEN;
    const int pstart = first_out - WARM;      // negative for chunk 0

    float psr[NSTEPS];
    #pragma unroll
    for (int s = 0; s < NSTEPS; ++s) psr[s] = ps[s];

    const int raddr = jc * 20;
    const int waddr = (i_mine >> 4) * 20 + (i_mine & 15);

    float prev = 0.0f;
    const int p0 = (pstart > 0) ? pstart : 0;
    float cur = emb[(size_t)ids[b * SEQ + p0] * D + i_mine];
    if (writer) sbuf[0][waddr] = cur;
    __syncthreads();

    for (int it = 0; it < ITERS; ++it) {
        const int pos = pstart + it;
        int pn = pos + 1;
        if (pn < 0) pn = 0;
        if (pn > SEQ - 1) pn = SEQ - 1;       // clamp (no OOB)
        float nxt = emb[(size_t)ids[b * SEQ + pn] * D + i_mine];  // prefetch
        const float ctx = (pos > 0) ? (1.0f / (float)(pos + 1)) : 0.0f;
        #pragma unroll
        for (int s = 0; s < NSTEPS; ++s) {
            const int rb = s & 1;
            const float4* sp = (const float4*)&sbuf[rb][raddr];
            float4 s0 = sp[0], s1 = sp[1], s2 = sp[2], s3 = sp[3];
            float a0 = 0.f, a1 = 0.f, a2 = 0.f, a3 = 0.f;
            #pragma unroll
            for (int q = 0; q < 4; ++q) {
                float4 sv = (q == 0) ? s0 : (q == 1) ? s1 : (q == 2) ? s2 : s3;
                a0 = fmaf(sv.x, wreg[0][q].x, a0); a0 = fmaf(sv.y, wreg[0][q].y, a0);
                a0 = fmaf(sv.z, wreg[0][q].z, a0); a0 = fmaf(sv.w, wreg[0][q].w, a0);
                a1 = fmaf(sv.x, wreg[1][q].x, a1); a1 = fmaf(sv.y, wreg[1][q].y, a1);
                a1 = fmaf(sv.z, wreg[1][q].z, a1); a1 = fmaf(sv.w, wreg[1][q].w, a1);
                a2 = fmaf(sv.x, wreg[2][q].x, a2); a2 = fmaf(sv.y, wreg[2][q].y, a2);
                a2 = fmaf(sv.z, wreg[2][q].z, a2); a2 = fmaf(sv.w, wreg[2][q].w, a2);
                a3 = fmaf(sv.x, wreg[3][q].x, a3); a3 = fmaf(sv.y, wreg[3][q].y, a3);
                a3 = fmaf(sv.z, wreg[3][q].z, a3); a3 = fmaf(sv.w, wreg[3][q].w, a3);
            }
            float k01 = (jc & 1) ? a1 : a0, s01 = (jc & 1) ? a0 : a1;
            float r01 = k01 + dpp_xor1(s01);
            float k23 = (jc & 1) ? a3 : a2, s23 = (jc & 1) ? a2 : a3;
            float r23 = k23 + dpp_xor1(s23);
            float k = (jc & 2) ? r23 : r01, sx = (jc & 2) ? r01 : r23;
            float v = k + dpp_xor2(sx);
            v += dpp_ror4(v);
            v += dpp_ror8(v);
            float x = fmaf(psr[s], cur, v);
            cur = gelu_fast(x) + ctx * prev;
            if (writer) sbuf[rb ^ 1][waddr] = (s == NSTEPS - 1) ? nxt : cur;
            __syncthreads();
        }
        prev = cur;   // NSTEPS even -> next pos reads buf0 (holds embeddings)
        if (pos >= first_out && writer)
            states[((size_t)(b * SEQ + pos)) * D + i_mine] = cur;
        cur = nxt;
    }
}

// ---------------------------------------------------------------------------
// Phase B: C[4096][32000] = states @ out_W^T + out_b.  R7/R11 kernel
// (2-term fp16 split + T14 register prefetch, bn-fast grid) with ONE change:
// NON-TEMPORAL C stores — the 512 MB write stream was evicting B (33 MB)
// from L3 (R9: FETCH 535 MB); streaming writes keep B resident.
// ---------------------------------------------------------------------------
#define BM 128
#define BN 128
#define BK 64
#define GT 512

__device__ __forceinline__ void split8(float4 a, float4 b, f16x8& hi, f16x8& lo) {
    float v[8] = {a.x, a.y, a.z, a.w, b.x, b.y, b.z, b.w};
    #pragma unroll
    for (int j = 0; j < 8; ++j) {
        _Float16 h = (_Float16)v[j];
        hi[j] = h;
        lo[j] = (_Float16)(v[j] - (float)h);
    }
}

__device__ __forceinline__ void cvt8(float4 a, float4 b, f16x8& hi) {
    float v[8] = {a.x, a.y, a.z, a.w, b.x, b.y, b.z, b.w};
    #pragma unroll
    for (int j = 0; j < 8; ++j) hi[j] = (_Float16)v[j];
}

__global__ __launch_bounds__(GT) void gemm_kernel(
    const float* __restrict__ A,    // [4096][256] states
    const float* __restrict__ Bw,   // [32000][256] out_W
    const float* __restrict__ bias, // [32000]
    float* __restrict__ C)          // [4096][32000]
{
    __shared__ _Float16 __align__(16) Ahi[BM * BK];
    __shared__ _Float16 __align__(16) Bhi[BN * BK], Blo[BN * BK];

    const int tid = (int)threadIdx.x;
    const int bn = blockIdx.x, bm = blockIdx.y;   // bn FAST (write locality)
    const int lane = tid & 63, wave = tid >> 6;
    const int wm = wave >> 2, wn = wave & 3;
    const int l15 = lane & 15, lh = lane >> 4;

    const int sr = tid >> 2;
    const int sg = tid & 3;

    const float* asrc = A  + (size_t)(bm * BM + sr) * D + sg * 16;
    const float* bsrc = Bw + (size_t)(bn * BN + sr) * D + sg * 16;

    f32x4 acc[4][2] = {};
    float4 av[4], bv[4];

    // prologue: load K-tile 0
    #pragma unroll
    for (int q = 0; q < 4; ++q) {
        av[q] = ((const float4*)asrc)[q];
        bv[q] = ((const float4*)bsrc)[q];
    }

    for (int kt = 0; kt < D; kt += BK) {
        // split + stage current tile
        {
            const int swzr = (sr & 7) << 4;
            #pragma unroll
            for (int h = 0; h < 2; ++h) {
                const int off = (sr * 128 + sg * 32 + h * 16) ^ swzr;
                f16x8 hi, lo;
                cvt8(av[h * 2], av[h * 2 + 1], hi);
                *(f16x8*)((char*)Ahi + off) = hi;
                split8(bv[h * 2], bv[h * 2 + 1], hi, lo);
                *(f16x8*)((char*)Bhi + off) = hi;
                *(f16x8*)((char*)Blo + off) = lo;
            }
        }
        __syncthreads();

        // T14: issue next K-tile's global loads BEFORE the MFMA cluster
        if (kt + BK < D) {
            const float* ap_ = asrc + kt + BK;
            const float* bp_ = bsrc + kt + BK;
            #pragma unroll
            for (int q = 0; q < 4; ++q) {
                av[q] = ((const float4*)ap_)[q];
                bv[q] = ((const float4*)bp_)[q];
            }
        }

        #pragma unroll
        for (int ks = 0; ks < 2; ++ks) {
            f16x8 ah[4], bh[2], bl[2];
            #pragma unroll
            for (int mt = 0; mt < 4; ++mt) {
                const int row = wm * 64 + mt * 16 + l15;
                const int off = (row * 128 + ks * 64 + lh * 16) ^ ((row & 7) << 4);
                ah[mt] = *(const f16x8*)((const char*)Ahi + off);
            }
            #pragma unroll
            for (int nt = 0; nt < 2; ++nt) {
                const int row = wn * 32 + nt * 16 + l15;
                const int off = (row * 128 + ks * 64 + lh * 16) ^ ((row & 7) << 4);
                bh[nt] = *(const f16x8*)((const char*)Bhi + off);
                bl[nt] = *(const f16x8*)((const char*)Blo + off);
            }
            #pragma unroll
            for (int mt = 0; mt < 4; ++mt)
                #pragma unroll
                for (int nt = 0; nt < 2; ++nt) {
                    acc[mt][nt] = __builtin_amdgcn_mfma_f32_16x16x32_f16(ah[mt], bh[nt], acc[mt][nt], 0, 0, 0);
                    acc[mt][nt] = __builtin_amdgcn_mfma_f32_16x16x32_f16(ah[mt], bl[nt], acc[mt][nt], 0, 0, 0);
                }
        }
        __syncthreads();
    }

    #pragma unroll
    for (int nt = 0; nt < 2; ++nt) {
        const int col = bn * BN + wn * 32 + nt * 16 + l15;
        const float bv2 = bias[col];
        #pragma unroll
        for (int mt = 0; mt < 4; ++mt) {
            const int row0 = bm * BM + wm * 64 + mt * 16 + lh * 4;
            #pragma unroll
            for (int r2 = 0; r2 < 4; ++r2)
                __builtin_nontemporal_store(acc[mt][nt][r2] + bv2,
                                            &C[(size_t)(row0 + r2) * VOCAB + col]);
        }
    }
}

extern "C" void kernel_launch(void* const* d_in, const int* in_sizes, int n_in,
                              void* d_out, int out_size, void* d_ws, size_t ws_size,
                              hipStream_t stream)
{
    const int*   ids  = (const int*)d_in[0];
    const float* emb  = (const float*)d_in[1];
    const float* W    = (const float*)d_in[2];
    const float* ps   = (const float*)d_in[3];
    const float* outW = (const float*)d_in[4];
    const float* outb = (const float*)d_in[5];
    float* out    = (float*)d_out;
    float* states = (float*)d_ws;   // [BATCH*SEQ][D] f32 = 4 MB

    scan_kernel<<<dim3(NCHUNK, BATCH), 1024, 0, stream>>>(ids, emb, W, ps, states);
    gemm_kernel<<<dim3(VOCAB / BN, (BATCH * SEQ) / BM), GT, 0, stream>>>(states, outW, outb, out);
}

// Round 14
// 432.200 us; speedup vs baseline: 1.0965x; 1.0965x over previous
//
#include <hip/hip_runtime.h>
#include <hip/hip_fp16.h>

#define VOCAB 32000
#define D 256
#define NSTEPS 12
#define BATCH 8
#define SEQ 512

// Uniform scan chunking: 32 chunks x 16 outputs, WARM=12 (validated R6/R7).
// pstart may be negative; ctx=0 at pos<=0 self-resets the recurrence.
#define OUTLEN 16
#define WARM 12
#define ITERS (OUTLEN + WARM)    // 28
#define NCHUNK (SEQ / OUTLEN)    // 32 -> 256 blocks, 1/CU

typedef _Float16 f16x8 __attribute__((ext_vector_type(8)));
typedef float f32x4 __attribute__((ext_vector_type(4)));

// gelu(x) = 0.5 x (1 + erf(x/sqrt(2))); erf via A&S 7.1.26 (|err|<=1.5e-7).
__device__ __forceinline__ float gelu_fast(float x) {
    float y = x * 0.70710678118654752440f;
    float a = fabsf(y);
    float t = __builtin_amdgcn_rcpf(fmaf(0.3275911f, a, 1.0f));
    float p = fmaf(t, 1.061405429f, -1.453152027f);
    p = fmaf(t, p, 1.421413741f);
    p = fmaf(t, p, -0.284496736f);
    p = fmaf(t, p, 0.254829592f);
    p *= t;
    float e = __expf(-a * a);
    float erf_y = copysignf(fmaf(-p, e, 1.0f), y);
    return 0.5f * x * (1.0f + erf_y);
}

// cross-lane helpers (all VALU, no DS port).
__device__ __forceinline__ float dpp_xor1(float v) {
    int r = __builtin_amdgcn_update_dpp(0, __float_as_int(v), 0xB1, 0xf, 0xf, true);
    return __int_as_float(r);
}
__device__ __forceinline__ float dpp_xor2(float v) {
    int r = __builtin_amdgcn_update_dpp(0, __float_as_int(v), 0x4E, 0xf, 0xf, true);
    return __int_as_float(r);
}
__device__ __forceinline__ float dpp_ror4(float v) {
    int r = __builtin_amdgcn_update_dpp(0, __float_as_int(v), 0x124, 0xf, 0xf, true);
    return __int_as_float(r);
}
__device__ __forceinline__ float dpp_ror8(float v) {
    int r = __builtin_amdgcn_update_dpp(0, __float_as_int(v), 0x128, 0xf, 0xf, true);
    return __int_as_float(r);
}

// ---------------------------------------------------------------------------
// Phase A scan — R4 structure (register-blocked O=4/J=16, DPP reduce, merged
// barrier) with uniform 28-iter chunking (OUTLEN=16, WARM=12).  (= R12 scan)
// ---------------------------------------------------------------------------
__global__ __launch_bounds__(1024) void scan_kernel(
    const int* __restrict__ ids, const float* __restrict__ emb,
    const float* __restrict__ W, const float* __restrict__ ps,
    float* __restrict__ states)
{
    const int chunk = blockIdx.x;
    const int b = blockIdx.y;
    const int t = (int)threadIdx.x;
    const int og = t >> 4;             // 0..63
    const int jc = t & 15;             // 0..15
    const int i_mine = og * 4 + (jc & 3);
    const bool writer = (jc < 4);

    float4 wreg[4][4];
    #pragma unroll
    for (int m = 0; m < 4; ++m) {
        const float4* wrow = (const float4*)(W + (og * 4 + m) * D + jc * 16);
        #pragma unroll
        for (int q = 0; q < 4; ++q) wreg[m][q] = wrow[q];
    }

    __shared__ __align__(16) float sbuf[2][16 * 20];

    const int first_out = chunk * OUTLEN;
    const int pstart = first_out - WARM;      // negative for chunk 0

    float psr[NSTEPS];
    #pragma unroll
    for (int s = 0; s < NSTEPS; ++s) psr[s] = ps[s];

    const int raddr = jc * 20;
    const int waddr = (i_mine >> 4) * 20 + (i_mine & 15);

    float prev = 0.0f;
    const int p0 = (pstart > 0) ? pstart : 0;
    float cur = emb[(size_t)ids[b * SEQ + p0] * D + i_mine];
    if (writer) sbuf[0][waddr] = cur;
    __syncthreads();

    for (int it = 0; it < ITERS; ++it) {
        const int pos = pstart + it;
        int pn = pos + 1;
        if (pn < 0) pn = 0;
        if (pn > SEQ - 1) pn = SEQ - 1;       // clamp (no OOB)
        float nxt = emb[(size_t)ids[b * SEQ + pn] * D + i_mine];  // prefetch
        const float ctx = (pos > 0) ? (1.0f / (float)(pos + 1)) : 0.0f;
        #pragma unroll
        for (int s = 0; s < NSTEPS; ++s) {
            const int rb = s & 1;
            const float4* sp = (const float4*)&sbuf[rb][raddr];
            float4 s0 = sp[0], s1 = sp[1], s2 = sp[2], s3 = sp[3];
            float a0 = 0.f, a1 = 0.f, a2 = 0.f, a3 = 0.f;
            #pragma unroll
            for (int q = 0; q < 4; ++q) {
                float4 sv = (q == 0) ? s0 : (q == 1) ? s1 : (q == 2) ? s2 : s3;
                a0 = fmaf(sv.x, wreg[0][q].x, a0); a0 = fmaf(sv.y, wreg[0][q].y, a0);
                a0 = fmaf(sv.z, wreg[0][q].z, a0); a0 = fmaf(sv.w, wreg[0][q].w, a0);
                a1 = fmaf(sv.x, wreg[1][q].x, a1); a1 = fmaf(sv.y, wreg[1][q].y, a1);
                a1 = fmaf(sv.z, wreg[1][q].z, a1); a1 = fmaf(sv.w, wreg[1][q].w, a1);
                a2 = fmaf(sv.x, wreg[2][q].x, a2); a2 = fmaf(sv.y, wreg[2][q].y, a2);
                a2 = fmaf(sv.z, wreg[2][q].z, a2); a2 = fmaf(sv.w, wreg[2][q].w, a2);
                a3 = fmaf(sv.x, wreg[3][q].x, a3); a3 = fmaf(sv.y, wreg[3][q].y, a3);
                a3 = fmaf(sv.z, wreg[3][q].z, a3); a3 = fmaf(sv.w, wreg[3][q].w, a3);
            }
            float k01 = (jc & 1) ? a1 : a0, s01 = (jc & 1) ? a0 : a1;
            float r01 = k01 + dpp_xor1(s01);
            float k23 = (jc & 1) ? a3 : a2, s23 = (jc & 1) ? a2 : a3;
            float r23 = k23 + dpp_xor1(s23);
            float k = (jc & 2) ? r23 : r01, sx = (jc & 2) ? r01 : r23;
            float v = k + dpp_xor2(sx);
            v += dpp_ror4(v);
            v += dpp_ror8(v);
            float x = fmaf(psr[s], cur, v);
            cur = gelu_fast(x) + ctx * prev;
            if (writer) sbuf[rb ^ 1][waddr] = (s == NSTEPS - 1) ? nxt : cur;
            __syncthreads();
        }
        prev = cur;   // NSTEPS even -> next pos reads buf0 (holds embeddings)
        if (pos >= first_out && writer)
            states[((size_t)(b * SEQ + pos)) * D + i_mine] = cur;
        cur = nxt;
    }
}

// ---------------------------------------------------------------------------
// Phase B: C[4096][32000] = states @ out_W^T + out_b.  R7/R11-EXACT kernel
// (2-term fp16 split + T14 register prefetch, bn-fast grid, PLAIN C stores —
// R12's nontemporal stores were the suspected +33 us regression).
// ---------------------------------------------------------------------------
#define BM 128
#define BN 128
#define BK 64
#define GT 512

__device__ __forceinline__ void split8(float4 a, float4 b, f16x8& hi, f16x8& lo) {
    float v[8] = {a.x, a.y, a.z, a.w, b.x, b.y, b.z, b.w};
    #pragma unroll
    for (int j = 0; j < 8; ++j) {
        _Float16 h = (_Float16)v[j];
        hi[j] = h;
        lo[j] = (_Float16)(v[j] - (float)h);
    }
}

__device__ __forceinline__ void cvt8(float4 a, float4 b, f16x8& hi) {
    float v[8] = {a.x, a.y, a.z, a.w, b.x, b.y, b.z, b.w};
    #pragma unroll
    for (int j = 0; j < 8; ++j) hi[j] = (_Float16)v[j];
}

__global__ __launch_bounds__(GT) void gemm_kernel(
    const float* __restrict__ A,    // [4096][256] states
    const float* __restrict__ Bw,   // [32000][256] out_W
    const float* __restrict__ bias, // [32000]
    float* __restrict__ C)          // [4096][32000]
{
    __shared__ _Float16 __align__(16) Ahi[BM * BK];
    __shared__ _Float16 __align__(16) Bhi[BN * BK], Blo[BN * BK];

    const int tid = (int)threadIdx.x;
    const int bn = blockIdx.x, bm = blockIdx.y;   // bn FAST (write locality)
    const int lane = tid & 63, wave = tid >> 6;
    const int wm = wave >> 2, wn = wave & 3;
    const int l15 = lane & 15, lh = lane >> 4;

    const int sr = tid >> 2;
    const int sg = tid & 3;

    const float* asrc = A  + (size_t)(bm * BM + sr) * D + sg * 16;
    const float* bsrc = Bw + (size_t)(bn * BN + sr) * D + sg * 16;

    f32x4 acc[4][2] = {};
    float4 av[4], bv[4];

    // prologue: load K-tile 0
    #pragma unroll
    for (int q = 0; q < 4; ++q) {
        av[q] = ((const float4*)asrc)[q];
        bv[q] = ((const float4*)bsrc)[q];
    }

    for (int kt = 0; kt < D; kt += BK) {
        // split + stage current tile
        {
            const int swzr = (sr & 7) << 4;
            #pragma unroll
            for (int h = 0; h < 2; ++h) {
                const int off = (sr * 128 + sg * 32 + h * 16) ^ swzr;
                f16x8 hi, lo;
                cvt8(av[h * 2], av[h * 2 + 1], hi);
                *(f16x8*)((char*)Ahi + off) = hi;
                split8(bv[h * 2], bv[h * 2 + 1], hi, lo);
                *(f16x8*)((char*)Bhi + off) = hi;
                *(f16x8*)((char*)Blo + off) = lo;
            }
        }
        __syncthreads();

        // T14: issue next K-tile's global loads BEFORE the MFMA cluster
        if (kt + BK < D) {
            const float* ap_ = asrc + kt + BK;
            const float* bp_ = bsrc + kt + BK;
            #pragma unroll
            for (int q = 0; q < 4; ++q) {
                av[q] = ((const float4*)ap_)[q];
                bv[q] = ((const float4*)bp_)[q];
            }
        }

        #pragma unroll
        for (int ks = 0; ks < 2; ++ks) {
            f16x8 ah[4], bh[2], bl[2];
            #pragma unroll
            for (int mt = 0; mt < 4; ++mt) {
                const int row = wm * 64 + mt * 16 + l15;
                const int off = (row * 128 + ks * 64 + lh * 16) ^ ((row & 7) << 4);
                ah[mt] = *(const f16x8*)((const char*)Ahi + off);
            }
            #pragma unroll
            for (int nt = 0; nt < 2; ++nt) {
                const int row = wn * 32 + nt * 16 + l15;
                const int off = (row * 128 + ks * 64 + lh * 16) ^ ((row & 7) << 4);
                bh[nt] = *(const f16x8*)((const char*)Bhi + off);
                bl[nt] = *(const f16x8*)((const char*)Blo + off);
            }
            #pragma unroll
            for (int mt = 0; mt < 4; ++mt)
                #pragma unroll
                for (int nt = 0; nt < 2; ++nt) {
                    acc[mt][nt] = __builtin_amdgcn_mfma_f32_16x16x32_f16(ah[mt], bh[nt], acc[mt][nt], 0, 0, 0);
                    acc[mt][nt] = __builtin_amdgcn_mfma_f32_16x16x32_f16(ah[mt], bl[nt], acc[mt][nt], 0, 0, 0);
                }
        }
        __syncthreads();
    }

    #pragma unroll
    for (int nt = 0; nt < 2; ++nt) {
        const int col = bn * BN + wn * 32 + nt * 16 + l15;
        const float bv2 = bias[col];
        #pragma unroll
        for (int mt = 0; mt < 4; ++mt) {
            const int row0 = bm * BM + wm * 64 + mt * 16 + lh * 4;
            #pragma unroll
            for (int r2 = 0; r2 < 4; ++r2)
                C[(size_t)(row0 + r2) * VOCAB + col] = acc[mt][nt][r2] + bv2;
        }
    }
}

extern "C" void kernel_launch(void* const* d_in, const int* in_sizes, int n_in,
                              void* d_out, int out_size, void* d_ws, size_t ws_size,
                              hipStream_t stream)
{
    const int*   ids  = (const int*)d_in[0];
    const float* emb  = (const float*)d_in[1];
    const float* W    = (const float*)d_in[2];
    const float* ps   = (const float*)d_in[3];
    const float* outW = (const float*)d_in[4];
    const float* outb = (const float*)d_in[5];
    float* out    = (float*)d_out;
    float* states = (float*)d_ws;   // [BATCH*SEQ][D] f32 = 4 MB

    scan_kernel<<<dim3(NCHUNK, BATCH), 1024, 0, stream>>>(ids, emb, W, ps, states);
    gemm_kernel<<<dim3(VOCAB / BN, (BATCH * SEQ) / BM), GT, 0, stream>>>(states, outW, outb, out);
}